// Round 5
// baseline (15.827 us; speedup 1.0000x reference)
//
#include <hip/hip_runtime.h>
#include <math.h>

#define SEQ 2048
#define DIME 128
#define BQ 16
#define NEG_INF -1.0e9f

typedef __attribute__((ext_vector_type(8))) short bf16x8;
typedef __attribute__((ext_vector_type(4))) float f32x4;

// f32 -> bf16 (round-nearest-even)
static __device__ __forceinline__ short f2b(float x) {
  union { float f; unsigned u; } v; v.f = x;
  unsigned r = v.u + 0x7FFF + ((v.u >> 16) & 1);
  return (short)(r >> 16);
}

static __device__ __forceinline__ bf16x8 pack8(const float4 lo, const float4 hi) {
  bf16x8 f;
  f[0] = f2b(lo.x); f[1] = f2b(lo.y); f[2] = f2b(lo.z); f[3] = f2b(lo.w);
  f[4] = f2b(hi.x); f[5] = f2b(hi.y); f[6] = f2b(hi.z); f[7] = f2b(hi.w);
  return f;
}

__global__ __launch_bounds__(256) void swa_kernel(
    const float* __restrict__ q, const float* __restrict__ k,
    const float* __restrict__ v, float* __restrict__ out) {
  // stride 18: S writes (rows 4g+r) and PV reads (rows 8g+j) both <=2-way (free)
  __shared__ float P[160][18];
  __shared__ float mW[9][16];
  __shared__ float sW[9][16];

  const int tid = threadIdx.x;
  const int lane = tid & 63;
  const int w = tid >> 6;      // wave 0..3
  const int col = lane & 15;
  const int g = lane >> 4;

  // 512 blocks = 2 dim-halves x (2 batches x 128 q-tiles).
  // h in the HIGH bits: both halves of a q-tile land on the same XCD (blk%8
  // unchanged) -> K/V window reads are L2-shared between the two blocks.
  const int blk = blockIdx.x;
  const int h = blk >> 8;          // dim-half: output dims [64h, 64h+64)
  const int tile = blk & 255;
  const int b = tile >> 7;
  const int qs = (tile & 127) * BQ;
  const int kbase = qs - 128;      // window slot 0 -> global key index

  const float* __restrict__ qb = q + (size_t)b * SEQ * DIME;
  const float* __restrict__ kb = k + (size_t)b * SEQ * DIME;
  const float* __restrict__ vb = v + (size_t)b * SEQ * DIME;

  // ---- issue Q loads first ----
  float4 qlo[4], qhi[4];
  {
    const float* qrow = qb + (size_t)(qs + col) * DIME + 8 * g;
#pragma unroll
    for (int kc = 0; kc < 4; ++kc) {
      qlo[kc] = *(const float4*)(qrow + 32 * kc);
      qhi[kc] = *(const float4*)(qrow + 32 * kc + 4);
    }
  }

  // ---- issue K loads (own tiles: {2w, 2w+1}, wave0 also tile 8) ----
  float4 kraw[3][8];
#pragma unroll
  for (int ti = 0; ti < 2; ++ti) {
    const int t = 2 * w + ti;
    int krow = kbase + 16 * t + col;
    krow = krow < 0 ? 0 : krow;
    const float* krp = kb + (size_t)krow * DIME + 8 * g;
#pragma unroll
    for (int kc = 0; kc < 4; ++kc) {
      kraw[ti][2 * kc]     = *(const float4*)(krp + 32 * kc);
      kraw[ti][2 * kc + 1] = *(const float4*)(krp + 32 * kc + 4);
    }
  }
  if (w == 0) {
    const int krow = kbase + 16 * 8 + col;   // always >= 0
    const float* krp = kb + (size_t)krow * DIME + 8 * g;
#pragma unroll
    for (int kc = 0; kc < 4; ++kc) {
      kraw[2][2 * kc]     = *(const float4*)(krp + 32 * kc);
      kraw[2][2 * kc + 1] = *(const float4*)(krp + 32 * kc + 4);
    }
  }

  // ---- issue V prefetch: wave w owns dims [64h+16w, 64h+16w+16) ----
  // B-fragment slot (g,j) of chunk c <- key kbase+32c+8g+j, dim col
  float vvf[5][8];
#pragma unroll
  for (int c = 0; c < 5; ++c)
#pragma unroll
    for (int j = 0; j < 8; ++j) {
      int kg = kbase + 32 * c + 8 * g + j;
      kg = kg < 0 ? 0 : (kg > SEQ - 1 ? SEQ - 1 : kg);
      vvf[c][j] = vb[(size_t)kg * DIME + 64 * h + 16 * w + col];
    }

  // ---- convert Q ----
  bf16x8 qf[4];
#pragma unroll
  for (int kc = 0; kc < 4; ++kc) qf[kc] = pack8(qlo[kc], qhi[kc]);

  // ---- zero P pad rows 144..159 (key slots beyond tile 8) ----
  P[144 + (tid >> 4)][tid & 15] = 0.f;

  // ---- S phase: per-tile QK^T, mask, per-tile softmax stats, stage P ----
  // S^T C-layout: row = key_local = 16t+4g+r, col = query (verified r2)
  const float scale = 0.08838834764831845f;  // 128^-0.5
  auto process = [&](int t, const float4 (&raw)[8]) {
    f32x4 acc = {0.f, 0.f, 0.f, 0.f};
#pragma unroll
    for (int kc = 0; kc < 4; ++kc)
      acc = __builtin_amdgcn_mfma_f32_16x16x32_bf16(
          pack8(raw[2 * kc], raw[2 * kc + 1]), qf[kc], acc, 0, 0, 0);
    float sc[4];
    float m = NEG_INF;
#pragma unroll
    for (int r = 0; r < 4; ++r) {
      const int kg = kbase + 16 * t + 4 * g + r;
      const int qg = qs + col;
      const bool valid = (kg >= 0) && (kg >= qg - 128) && (kg <= qg);
      sc[r] = valid ? acc[r] * scale : NEG_INF;
      m = fmaxf(m, sc[r]);
    }
    m = fmaxf(m, __shfl_xor(m, 16));
    m = fmaxf(m, __shfl_xor(m, 32));
    float s = 0.f;
#pragma unroll
    for (int r = 0; r < 4; ++r) { sc[r] = __expf(sc[r] - m); s += sc[r]; }
    s += __shfl_xor(s, 16);
    s += __shfl_xor(s, 32);
    if (g == 0) { mW[t][col] = m; sW[t][col] = s; }
#pragma unroll
    for (int r = 0; r < 4; ++r) P[16 * t + 4 * g + r][col] = sc[r];
  };
  process(2 * w, kraw[0]);
  process(2 * w + 1, kraw[1]);
  if (w == 0) process(8, kraw[2]);

  __syncthreads();   // the ONLY barrier

  // ---- per-lane softmax combine (redundant across lanes; broadcast LDS reads)
  // scale for tile t folds normalization: e(m_t - M) / S_total
  float M = mW[0][col];
#pragma unroll
  for (int t = 1; t < 9; ++t) M = fmaxf(M, mW[t][col]);
  float e[9], St = 0.f;
#pragma unroll
  for (int t = 0; t < 9; ++t) {
    e[t] = __expf(mW[t][col] - M);
    St += sW[t][col] * e[t];
  }
  const float inv = 1.0f / St;
  float swt[5];   // per-chunk scale; chunk c covers tiles {2c, 2c+1}; this
                  // lane's keys (8g+j) fall in tile 2c + (g>>1)
#pragma unroll
  for (int c = 0; c < 5; ++c) {
    const float ehi = (2 * c + 1 < 9) ? e[2 * c + 1] : 0.f;  // tile 9 = pad
    swt[c] = ((g >> 1) ? ehi : e[2 * c]) * inv;
  }

  // ---- PV: contract 160 key slots; V already in registers; 5 MFMAs ----
  f32x4 o = {0.f, 0.f, 0.f, 0.f};
#pragma unroll
  for (int c = 0; c < 5; ++c) {
    bf16x8 pa, bv;
#pragma unroll
    for (int j = 0; j < 8; ++j) {
      pa[j] = f2b(P[32 * c + 8 * g + j][col] * swt[c]);  // A: row=q(col), k=key
      bv[j] = f2b(vvf[c][j]);                            // B: k=key, col=dim
    }
    o = __builtin_amdgcn_mfma_f32_16x16x32_bf16(pa, bv, o, 0, 0, 0);
  }

  // ---- store: C row = q = 4g+r, col -> dim 64h + 16w + col ----
#pragma unroll
  for (int r = 0; r < 4; ++r) {
    const int qrow = 4 * g + r;
    out[(size_t)(b * SEQ + qs + qrow) * DIME + 64 * h + 16 * w + col] = o[r];
  }
}

extern "C" void kernel_launch(void* const* d_in, const int* in_sizes, int n_in,
                              void* d_out, int out_size, void* d_ws, size_t ws_size,
                              hipStream_t stream) {
  const float* q = (const float*)d_in[0];
  const float* k = (const float*)d_in[1];
  const float* v = (const float*)d_in[2];
  float* out = (float*)d_out;
  // 2 dim-halves x 2 batches x 128 q-tiles = 512 blocks, 4 waves each
  dim3 grid(512), block(256);
  swa_kernel<<<grid, block, 0, stream>>>(q, k, v, out);
}

// Round 6
// 12.381 us; speedup vs baseline: 1.2783x; 1.2783x over previous
//
#include <hip/hip_runtime.h>
#include <hip/hip_bf16.h>
#include <math.h>

#define SEQ 2048
#define DIME 128
#define BQ 16
#define NEG_INF -1.0e9f

typedef __attribute__((ext_vector_type(8))) short bf16x8;
typedef __attribute__((ext_vector_type(4))) float f32x4;

// f32 -> bf16 via compiler path (emits v_cvt_pk_bf16_f32 when paired)
static __device__ __forceinline__ short cvt(float x) {
  __hip_bfloat16 h(x);
  return __builtin_bit_cast(short, h);
}

static __device__ __forceinline__ bf16x8 pack8(const float4 lo, const float4 hi) {
  bf16x8 f;
  f[0] = cvt(lo.x); f[1] = cvt(lo.y); f[2] = cvt(lo.z); f[3] = cvt(lo.w);
  f[4] = cvt(hi.x); f[5] = cvt(hi.y); f[6] = cvt(hi.z); f[7] = cvt(hi.w);
  return f;
}

__global__ __launch_bounds__(256) void swa_kernel(
    const float* __restrict__ q, const float* __restrict__ k,
    const float* __restrict__ v, float* __restrict__ out) {
  // P[q][keyslot], pad 180 (mod32=20): tile writes (b128 at 16t+4g) and PV
  // reads (b128 at 32c+8g) are <=2-way bank aliased (free per m136).
  __shared__ float P[16][180];
  __shared__ float mW[9][16];
  __shared__ float sW[9][16];

  const int tid = threadIdx.x;
  const int lane = tid & 63;
  const int w = tid >> 6;      // wave 0..3
  const int col = lane & 15;
  const int g = lane >> 4;

  const int blk = blockIdx.x;  // 256 blocks: 128 q-tiles x 2 batches
  const int b = blk >> 7;
  const int qs = (blk & 127) * BQ;
  const int kbase = qs - 128;  // window slot 0 -> global key index

  const float* __restrict__ qb = q + (size_t)b * SEQ * DIME;
  const float* __restrict__ kb = k + (size_t)b * SEQ * DIME;
  const float* __restrict__ vb = v + (size_t)b * SEQ * DIME;

  // ---- issue Q loads first ----
  float4 qlo[4], qhi[4];
  {
    const float* qrow = qb + (size_t)(qs + col) * DIME + 8 * g;
#pragma unroll
    for (int kc = 0; kc < 4; ++kc) {
      qlo[kc] = *(const float4*)(qrow + 32 * kc);
      qhi[kc] = *(const float4*)(qrow + 32 * kc + 4);
    }
  }

  // ---- issue K loads (own tiles: {2w, 2w+1}, wave0 also tile 8) ----
  float4 kraw[3][8];
#pragma unroll
  for (int ti = 0; ti < 2; ++ti) {
    const int t = 2 * w + ti;
    int krow = kbase + 16 * t + col;
    krow = krow < 0 ? 0 : krow;
    const float* krp = kb + (size_t)krow * DIME + 8 * g;
#pragma unroll
    for (int kc = 0; kc < 4; ++kc) {
      kraw[ti][2 * kc]     = *(const float4*)(krp + 32 * kc);
      kraw[ti][2 * kc + 1] = *(const float4*)(krp + 32 * kc + 4);
    }
  }
  if (w == 0) {
    const int krow = kbase + 16 * 8 + col;   // always >= 0
    const float* krp = kb + (size_t)krow * DIME + 8 * g;
#pragma unroll
    for (int kc = 0; kc < 4; ++kc) {
      kraw[2][2 * kc]     = *(const float4*)(krp + 32 * kc);
      kraw[2][2 * kc + 1] = *(const float4*)(krp + 32 * kc + 4);
    }
  }

  // ---- issue V prefetch: wave w owns dims [32w, 32w+32) as pairs 2col,2col+1
  float2 vv[5][8];
#pragma unroll
  for (int c = 0; c < 5; ++c)
#pragma unroll
    for (int j = 0; j < 8; ++j) {
      int kg = kbase + 32 * c + 8 * g + j;
      kg = kg < 0 ? 0 : (kg > SEQ - 1 ? SEQ - 1 : kg);
      vv[c][j] = *(const float2*)(vb + (size_t)kg * DIME + 32 * w + 2 * col);
    }

  // ---- zero P pad slots 144..159 (beyond tile 8) ----
  P[tid >> 4][144 + (tid & 15)] = 0.f;

  // ---- convert Q (in-order vmcnt: waits only on Q) ----
  bf16x8 qf[4];
#pragma unroll
  for (int kc = 0; kc < 4; ++kc) qf[kc] = pack8(qlo[kc], qhi[kc]);

  // ---- S phase: QK^T per tile, mask, per-tile stats, stage P (b128) ----
  // S^T C-layout: row = key_local = 16t+4g+r, col = query (verified r2)
  const float scale = 0.08838834764831845f;  // 128^-0.5
  auto process = [&](int t, const float4 (&raw)[8]) {
    f32x4 acc = {0.f, 0.f, 0.f, 0.f};
#pragma unroll
    for (int kc = 0; kc < 4; ++kc)
      acc = __builtin_amdgcn_mfma_f32_16x16x32_bf16(
          pack8(raw[2 * kc], raw[2 * kc + 1]), qf[kc], acc, 0, 0, 0);
    float sc[4];
    float m = NEG_INF;
#pragma unroll
    for (int r = 0; r < 4; ++r) {
      const int kg = kbase + 16 * t + 4 * g + r;
      const int qg = qs + col;
      const bool valid = (kg >= 0) && (kg >= qg - 128) && (kg <= qg);
      sc[r] = valid ? acc[r] * scale : NEG_INF;
      m = fmaxf(m, sc[r]);
    }
    m = fmaxf(m, __shfl_xor(m, 16));
    m = fmaxf(m, __shfl_xor(m, 32));
    float s = 0.f;
#pragma unroll
    for (int r = 0; r < 4; ++r) { sc[r] = __expf(sc[r] - m); s += sc[r]; }
    s += __shfl_xor(s, 16);
    s += __shfl_xor(s, 32);
    if (g == 0) { mW[t][col] = m; sW[t][col] = s; }
    const float4 scv = {sc[0], sc[1], sc[2], sc[3]};
    *(float4*)&P[col][16 * t + 4 * g] = scv;   // one ds_write_b128
  };
  process(2 * w, kraw[0]);
  process(2 * w + 1, kraw[1]);
  if (w == 0) process(8, kraw[2]);

  __syncthreads();   // the ONLY barrier

  // ---- per-lane softmax combine (scale folds normalization) ----
  float M = mW[0][col];
#pragma unroll
  for (int t = 1; t < 9; ++t) M = fmaxf(M, mW[t][col]);
  float e[9], St = 0.f;
#pragma unroll
  for (int t = 0; t < 9; ++t) {
    e[t] = __expf(mW[t][col] - M);
    St += sW[t][col] * e[t];
  }
  const float inv = 1.0f / St;
  float swt[5];   // chunk c: this lane's keys (slots 32c+8g+j) are in tile 2c+(g>>1)
#pragma unroll
  for (int c = 0; c < 5; ++c) {
    const float ehi = (2 * c + 1 < 9) ? e[2 * c + 1] : 0.f;  // tile 9 = pad
    swt[c] = ((g >> 1) ? ehi : e[2 * c]) * inv;
  }

  // ---- PV: 160 key slots, V in registers, P via 2x ds_read_b128/chunk ----
  f32x4 o0 = {0.f, 0.f, 0.f, 0.f}, o1 = {0.f, 0.f, 0.f, 0.f};
#pragma unroll
  for (int c = 0; c < 5; ++c) {
    const float4 pA = *(const float4*)&P[col][32 * c + 8 * g];
    const float4 pB = *(const float4*)&P[col][32 * c + 8 * g + 4];
    bf16x8 pa, b0, b1;
    pa[0] = cvt(pA.x * swt[c]); pa[1] = cvt(pA.y * swt[c]);
    pa[2] = cvt(pA.z * swt[c]); pa[3] = cvt(pA.w * swt[c]);
    pa[4] = cvt(pB.x * swt[c]); pa[5] = cvt(pB.y * swt[c]);
    pa[6] = cvt(pB.z * swt[c]); pa[7] = cvt(pB.w * swt[c]);
#pragma unroll
    for (int j = 0; j < 8; ++j) {
      b0[j] = cvt(vv[c][j].x);   // B: k=key, col -> dim 32w + 2n
      b1[j] = cvt(vv[c][j].y);   //                  dim 32w + 2n+1
    }
    o0 = __builtin_amdgcn_mfma_f32_16x16x32_bf16(pa, b0, o0, 0, 0, 0);
    o1 = __builtin_amdgcn_mfma_f32_16x16x32_bf16(pa, b1, o1, 0, 0, 0);
  }

  // ---- store: C row = q = 4g+r, col -> dims 32w + 2col + {0,1} ----
#pragma unroll
  for (int r = 0; r < 4; ++r) {
    const int qrow = 4 * g + r;
    float2 val = {o0[r], o1[r]};
    *(float2*)&out[(size_t)(b * SEQ + qs + qrow) * DIME + 32 * w + 2 * col] = val;
  }
}

extern "C" void kernel_launch(void* const* d_in, const int* in_sizes, int n_in,
                              void* d_out, int out_size, void* d_ws, size_t ws_size,
                              hipStream_t stream) {
  const float* q = (const float*)d_in[0];
  const float* k = (const float*)d_in[1];
  const float* v = (const float*)d_in[2];
  float* out = (float*)d_out;
  // 2 batches x 128 q-tiles of 16 queries = 256 blocks, 4 waves each
  dim3 grid(256), block(256);
  swa_kernel<<<grid, block, 0, stream>>>(q, k, v, out);
}